// Round 5
// baseline (436.711 us; speedup 1.0000x reference)
//
#include <hip/hip_runtime.h>
#include <hip/hip_fp16.h>
#include <hip/hip_bf16.h>

#define IN_DIM 256
#define HID_DIM 128
#define OUT_DIM 64

typedef short s8v __attribute__((ext_vector_type(8)));
typedef float f32x4 __attribute__((ext_vector_type(4)));

// ---------------- bf16 split helpers ----------------

__device__ __forceinline__ unsigned short bf16_rne(float f) {
    unsigned int u = __float_as_uint(f);
    u += 0x7FFFu + ((u >> 16) & 1u);
    return (unsigned short)(u >> 16);
}
__device__ __forceinline__ float bfbits_to_f(unsigned short h) {
    return __uint_as_float(((unsigned int)h) << 16);
}

// 8 consecutive floats -> hi/lo bf16 fragments via v_cvt_pk_bf16_f32
__device__ __forceinline__ void cvt_split8(float4 f0, float4 f1, s8v& hi, s8v& lo) {
    float fv[8] = {f0.x, f0.y, f0.z, f0.w, f1.x, f1.y, f1.z, f1.w};
    unsigned int hw[4], lw[4];
#pragma unroll
    for (int i = 0; i < 4; i++) {
        __hip_bfloat162 hh = __float22bfloat162_rn(make_float2(fv[2*i], fv[2*i+1]));
        unsigned int hb = *(unsigned int*)&hh;
        float r0 = __uint_as_float(hb << 16);
        float r1 = __uint_as_float(hb & 0xffff0000u);
        __hip_bfloat162 ll = __float22bfloat162_rn(
            make_float2(fv[2*i] - r0, fv[2*i+1] - r1));
        hw[i] = hb;
        lw[i] = *(unsigned int*)&ll;
    }
    hi = *(s8v*)hw;
    lo = *(s8v*)lw;
}

__global__ __launch_bounds__(256) void wsplit_kernel(const float* __restrict__ W,
        unsigned short* __restrict__ wth, unsigned short* __restrict__ wtl,
        int K, int NCOL) {
    int idx = blockIdx.x * 256 + threadIdx.x;
    if (idx < K * NCOL) {
        int k = idx / NCOL, nn = idx % NCOL;
        float f = W[idx];
        unsigned short h = bf16_rne(f);
        unsigned short l = bf16_rne(f - bfbits_to_f(h));
        wth[nn * K + k] = h;
        wtl[nn * K + k] = l;
    }
}

// ---------------- preprocessing ----------------
// packed[i]: bits [63:40] = edge count, bits [39:0] = fixed-point (2^-24) sum of w.

#define FPSCALE 16777216.0f
#define FPMASK  ((1ULL << 40) - 1)

__global__ __launch_bounds__(256) void init_kernel(unsigned long long* packed, int n) {
    int i = blockIdx.x * 256 + threadIdx.x;
    if (i < n) packed[i] = (1ULL << 24);      // deg = 1.0 (self-loop), cnt = 0
}

__global__ __launch_bounds__(256) void dinv_kernel(const unsigned long long* __restrict__ packed,
        float* __restrict__ dinv, int* __restrict__ cnt, int n) {
    int i = blockIdx.x * 256 + threadIdx.x;
    if (i < n) {
        unsigned long long p = packed[i];
        float d = (float)(p & FPMASK) * (1.0f / FPSCALE);
        dinv[i] = d > 0.0f ? rsqrtf(d) : 0.0f;
        cnt[i] = (int)(p >> 40);
    }
}

// ---- hierarchical exclusive scan ----

__global__ __launch_bounds__(256) void scan1_kernel(const int* __restrict__ cnt,
        int* __restrict__ bsum, int n) {
    int t = threadIdx.x;
    int base = blockIdx.x * 1024 + t * 4;
    int s = 0;
    if (base + 3 < n) {
        int4 v = *(const int4*)(cnt + base);
        s = v.x + v.y + v.z + v.w;
    } else {
        for (int i = 0; i < 4; i++) if (base + i < n) s += cnt[base + i];
    }
    __shared__ int sm[256];
    sm[t] = s;
    __syncthreads();
    for (int d = 1; d < 256; d <<= 1) {
        int v = (t >= d) ? sm[t - d] : 0;
        __syncthreads();
        sm[t] += v;
        __syncthreads();
    }
    if (t == 255) bsum[blockIdx.x] = sm[255];
}

__global__ __launch_bounds__(1024) void scan2_kernel(int* bsum, int* total_out, int nb) {
    __shared__ int sm[1024];
    int t = threadIdx.x;
    int v = (t < nb) ? bsum[t] : 0;
    sm[t] = v;
    __syncthreads();
    for (int d = 1; d < 1024; d <<= 1) {
        int u = (t >= d) ? sm[t - d] : 0;
        __syncthreads();
        sm[t] += u;
        __syncthreads();
    }
    int ex = (t == 0) ? 0 : sm[t - 1];
    if (t < nb) bsum[t] = ex;
    if (t == nb - 1) *total_out = sm[t];
}

__global__ __launch_bounds__(256) void scan3_kernel(const int* __restrict__ cnt,
        const int* __restrict__ bsum, int* __restrict__ offsets, int n) {
    int t = threadIdx.x;
    int base = blockIdx.x * 1024 + t * 4;
    int a[4] = {0, 0, 0, 0};
    if (base + 3 < n) {
        int4 v = *(const int4*)(cnt + base);
        a[0] = v.x; a[1] = v.y; a[2] = v.z; a[3] = v.w;
    } else {
        for (int i = 0; i < 4; i++) if (base + i < n) a[i] = cnt[base + i];
    }
    int s = a[0] + a[1] + a[2] + a[3];
    __shared__ int sm[256];
    sm[t] = s;
    __syncthreads();
    for (int d = 1; d < 256; d <<= 1) {
        int u = (t >= d) ? sm[t - d] : 0;
        __syncthreads();
        sm[t] += u;
        __syncthreads();
    }
    int pre = bsum[blockIdx.x] + ((t == 0) ? 0 : sm[t - 1]);
    int o0 = pre, o1 = o0 + a[0], o2 = o1 + a[1], o3 = o2 + a[2];
    if (base + 3 < n) {
        *(int4*)(offsets + base) = make_int4(o0, o1, o2, o3);
    } else {
        int o[4] = {o0, o1, o2, o3};
        for (int i = 0; i < 4; i++) if (base + i < n) offsets[base + i] = o[i];
    }
}

// CSC entry: int2{ src_row, float_bits(w * dinv[src]) }.
// No atomic: slot = offsets[col] + arrival index from the fused deg pass.

__global__ __launch_bounds__(256) void fill_csc_kernel(const int* __restrict__ row,
        const int* __restrict__ col, const float* __restrict__ w,
        const float* __restrict__ dinv,
        const int* __restrict__ offsets, const int* __restrict__ arr,
        int2* __restrict__ csc, int e) {
    int i = blockIdx.x * 256 + threadIdx.x;
    if (i < e) {
        int c = col[i];
        int r = row[i];
        int p = offsets[c] + arr[i];
        csc[p] = make_int2(r, __float_as_int(w[i] * dinv[r]));
    }
}

// ---------------- fused MFMA GEMM + deg/cnt atomics -------------------------
// Blocks [0, gemmBlocks): split-bf16 GEMM (M=64/wave, XOR-swizzled B staging
// via global_load_lds, A global->reg). Writes UNSCALED x@W in fp16.
// Blocks [gemmBlocks, ...): 1024 edges/block; all 8 u64 atomics issued before
// any return is consumed (1 stall round per wave instead of 2).

template<int K, int NCOL, bool DEG>
__global__ __launch_bounds__(128, 2) void gemm_deg_kernel(
        const float* __restrict__ x, const unsigned short* __restrict__ wth,
        const unsigned short* __restrict__ wtl,
        __half* __restrict__ out, int n, int gemmBlocks,
        const int* __restrict__ colIdx, const float* __restrict__ ew,
        unsigned long long* packed, int* __restrict__ arr, int eCount) {
    constexpr int NT = NCOL / 16;          // 16-col tiles
    constexpr int NCH = K / 32;            // K chunks
    constexpr int NS = NCOL / 16;          // 16-row B segments per chunk

    __shared__ unsigned short sBh[2][NCOL][32];
    __shared__ unsigned short sBl[2][NCOL][32];

    int t = threadIdx.x;

    if (DEG && (int)blockIdx.x >= gemmBlocks) {
        // ---- edge-atomic role ----
        long ebase = (long)((int)blockIdx.x - gemmBlocks) * 1024;
        long i0 = ebase + t * 4;
        long i1 = ebase + 512 + t * 4;
        if (i1 + 3 < eCount) {
            int4 c0 = *(const int4*)(colIdx + i0);
            float4 w0 = *(const float4*)(ew + i0);
            int4 c1 = *(const int4*)(colIdx + i1);
            float4 w1 = *(const float4*)(ew + i1);
            unsigned long long o0 = atomicAdd(&packed[c0.x],
                (1ULL << 40) | (unsigned long long)(w0.x * FPSCALE + 0.5f));
            unsigned long long o1 = atomicAdd(&packed[c0.y],
                (1ULL << 40) | (unsigned long long)(w0.y * FPSCALE + 0.5f));
            unsigned long long o2 = atomicAdd(&packed[c0.z],
                (1ULL << 40) | (unsigned long long)(w0.z * FPSCALE + 0.5f));
            unsigned long long o3 = atomicAdd(&packed[c0.w],
                (1ULL << 40) | (unsigned long long)(w0.w * FPSCALE + 0.5f));
            unsigned long long o4 = atomicAdd(&packed[c1.x],
                (1ULL << 40) | (unsigned long long)(w1.x * FPSCALE + 0.5f));
            unsigned long long o5 = atomicAdd(&packed[c1.y],
                (1ULL << 40) | (unsigned long long)(w1.y * FPSCALE + 0.5f));
            unsigned long long o6 = atomicAdd(&packed[c1.z],
                (1ULL << 40) | (unsigned long long)(w1.z * FPSCALE + 0.5f));
            unsigned long long o7 = atomicAdd(&packed[c1.w],
                (1ULL << 40) | (unsigned long long)(w1.w * FPSCALE + 0.5f));
            *(int4*)(arr + i0) = make_int4((int)(o0 >> 40), (int)(o1 >> 40),
                                           (int)(o2 >> 40), (int)(o3 >> 40));
            *(int4*)(arr + i1) = make_int4((int)(o4 >> 40), (int)(o5 >> 40),
                                           (int)(o6 >> 40), (int)(o7 >> 40));
        } else {
            for (int j = 0; j < 2; j++) {
                long i = (j == 0) ? i0 : i1;
                for (int q = 0; q < 4; q++) {
                    long ii = i + q;
                    if (ii < eCount) {
                        unsigned long long v = (1ULL << 40) |
                            (unsigned long long)(ew[ii] * FPSCALE + 0.5f);
                        unsigned long long old = atomicAdd(&packed[colIdx[ii]], v);
                        arr[ii] = (int)(old >> 40);
                    }
                }
            }
        }
        return;
    }

    // ---- GEMM role ----
    int wave = t >> 6, lane = t & 63, quad = lane >> 4, r16 = lane & 15;
    long rowBase = (long)blockIdx.x * 128 + wave * 64;

    f32x4 acc[4][NT];
#pragma unroll
    for (int mi = 0; mi < 4; mi++)
#pragma unroll
        for (int nt = 0; nt < NT; nt++) acc[mi][nt] = (f32x4)0.0f;

    const float* pa[4];
#pragma unroll
    for (int mi = 0; mi < 4; mi++) {
        long r = rowBase + mi * 16 + r16;
        if (r > n - 1) r = n - 1;
        pa[mi] = x + r * K + quad * 8;
    }

    // staging: lane l writes phys (row=l>>2, slot=l&3); fetch logical slot =
    // phys ^ sw(row), sw(row)=(row>>1)&3  (both-sides XOR swizzle).
    int srcSlot = ((lane & 3) ^ ((lane >> 3) & 3)) * 8;   // in shorts
    int lrow = lane >> 2;

    auto stage = [&](int buf, int kc) {
#pragma unroll
        for (int j = 0; j < NS / 2; j++) {
            int s = wave + 2 * j;                 // 16-row segment id
            int r = s * 16 + lrow;                // B row (= output col)
            const unsigned short* gh = wth + (long)r * K + kc * 32 + srcSlot;
            const unsigned short* gl = wtl + (long)r * K + kc * 32 + srcSlot;
            __builtin_amdgcn_global_load_lds(
                (const __attribute__((address_space(1))) unsigned int*)gh,
                (__attribute__((address_space(3))) unsigned int*)&sBh[buf][s * 16][0],
                16, 0, 0);
            __builtin_amdgcn_global_load_lds(
                (const __attribute__((address_space(1))) unsigned int*)gl,
                (__attribute__((address_space(3))) unsigned int*)&sBl[buf][s * 16][0],
                16, 0, 0);
        }
    };

    // prologue: stage chunk 0, prefetch A chunk 0
    stage(0, 0);
    float4 a[8];
#pragma unroll
    for (int mi = 0; mi < 4; mi++) {
        a[2 * mi]     = *(const float4*)(pa[mi]);
        a[2 * mi + 1] = *(const float4*)(pa[mi] + 4);
    }
    __syncthreads();

    int rdSlot = (r16 >> 1) & 3;    // read-side swizzle component

    for (int kc = 0; kc < NCH; kc++) {
        int buf = kc & 1;
        if (kc + 1 < NCH) stage(buf ^ 1, kc + 1);   // B prefetch over MFMA

        s8v ah[4], al[4];
#pragma unroll
        for (int mi = 0; mi < 4; mi++)
            cvt_split8(a[2 * mi], a[2 * mi + 1], ah[mi], al[mi]);
        if (kc + 1 < NCH) {                          // A register prefetch
#pragma unroll
            for (int mi = 0; mi < 4; mi++) {
                const float* q = pa[mi] + (kc + 1) * 32;
                a[2 * mi]     = *(const float4*)(q);
                a[2 * mi + 1] = *(const float4*)(q + 4);
            }
        }
#pragma unroll
        for (int nt = 0; nt < NT; nt++) {
            int sl = (quad ^ rdSlot) * 8;
            s8v bh = *(const s8v*)&sBh[buf][nt * 16 + r16][sl];
            s8v bl = *(const s8v*)&sBl[buf][nt * 16 + r16][sl];
#pragma unroll
            for (int mi = 0; mi < 4; mi++) {
                acc[mi][nt] = __builtin_amdgcn_mfma_f32_16x16x32_bf16(ah[mi], bh, acc[mi][nt], 0, 0, 0);
                acc[mi][nt] = __builtin_amdgcn_mfma_f32_16x16x32_bf16(al[mi], bh, acc[mi][nt], 0, 0, 0);
                acc[mi][nt] = __builtin_amdgcn_mfma_f32_16x16x32_bf16(ah[mi], bl, acc[mi][nt], 0, 0, 0);
            }
        }
        __syncthreads();   // drains stage(kc+1) + flips buffers
    }

#pragma unroll
    for (int mi = 0; mi < 4; mi++) {
        long gr0 = rowBase + mi * 16 + quad * 4;
#pragma unroll
        for (int nt = 0; nt < NT; nt++) {
            f32x4 d = acc[mi][nt];
#pragma unroll
            for (int i = 0; i < 4; i++) {
                long gr = gr0 + i;
                if (gr < n) out[gr * NCOL + nt * 16 + r16] = __float2half(d[i]);
            }
        }
    }
}

// ---------------- fp16 gather accumulate helpers ----------------

__device__ __forceinline__ void acc8(float* a, uint4 raw, float w) {
    __half2* hp = (__half2*)&raw;
    float2 f0 = __half22float2(hp[0]);
    float2 f1 = __half22float2(hp[1]);
    float2 f2 = __half22float2(hp[2]);
    float2 f3 = __half22float2(hp[3]);
    a[0] += w * f0.x; a[1] += w * f0.y; a[2] += w * f1.x; a[3] += w * f1.y;
    a[4] += w * f2.x; a[5] += w * f2.y; a[6] += w * f3.x; a[7] += w * f3.y;
}

__device__ __forceinline__ void acc4h(float* a, uint2 raw, float w) {
    __half2* hp = (__half2*)&raw;
    float2 f0 = __half22float2(hp[0]);
    float2 f1 = __half22float2(hp[1]);
    a[0] += w * f0.x; a[1] += w * f0.y; a[2] += w * f1.x; a[3] += w * f1.y;
}

// ---------------- aggregation layer 1 (D=128 fp16 in, fp32 out, +bias, relu) ----
// h rows are UNSCALED; csc weight is w*dinv[src]; self weight dinv[node];
// final scale dinv[node]. 4 independent accumulator streams per strm-slice:
// each strm consumes 4 edges per iteration (wave stride 16), so the wave keeps
// 4 row-gathers in flight instead of 2 — agg is L3-latency-bound (h table is
// 25.6 MB, fully L3-resident; gather traffic 410 MB never touches HBM).

__global__ __launch_bounds__(256) void agg1_kernel(const __half* __restrict__ h,
        const float* __restrict__ dinv, const int* __restrict__ offsets,
        const int2* __restrict__ csc, const float* __restrict__ b,
        float* __restrict__ out, int n) {
    int t = threadIdx.x;
    int lane = t & 63;
    int strm = lane >> 4;            // 0..3
    int li = lane & 15;              // half8 index in row (16*8 = 128 dims)
    int node = blockIdx.x * 4 + (t >> 6);
    if (node >= n) return;

    float di = dinv[node];
    float a0[8] = {0,0,0,0,0,0,0,0};
    float a1[8] = {0,0,0,0,0,0,0,0};
    float a2[8] = {0,0,0,0,0,0,0,0};
    float a3[8] = {0,0,0,0,0,0,0,0};
    int s = offsets[node], e = offsets[node + 1];

    if (strm == 0) {                 // self-loop: weight dinv[node] * h[node]
        uint4 raw = ((const uint4*)(h + (long)node * HID_DIM))[li];
        acc8(a0, raw, di);
    }

    int p = s + strm;
    for (; p + 12 < e; p += 16) {    // 4 edges per strm per iteration
        int2 e0 = csc[p], e1 = csc[p + 4], e2 = csc[p + 8], e3 = csc[p + 12];
        uint4 r0 = ((const uint4*)(h + (long)e0.x * HID_DIM))[li];
        uint4 r1 = ((const uint4*)(h + (long)e1.x * HID_DIM))[li];
        uint4 r2 = ((const uint4*)(h + (long)e2.x * HID_DIM))[li];
        uint4 r3 = ((const uint4*)(h + (long)e3.x * HID_DIM))[li];
        acc8(a0, r0, __int_as_float(e0.y));
        acc8(a1, r1, __int_as_float(e1.y));
        acc8(a2, r2, __int_as_float(e2.y));
        acc8(a3, r3, __int_as_float(e3.y));
    }
    // tail: up to 3 edges left on this strm (issue loads first, then acc)
    {
        bool v0 = (p < e), v1 = (p + 4 < e), v2 = (p + 8 < e);
        int2 e0, e1, e2;
        uint4 r0, r1, r2;
        if (v0) { e0 = csc[p];     r0 = ((const uint4*)(h + (long)e0.x * HID_DIM))[li]; }
        if (v1) { e1 = csc[p + 4]; r1 = ((const uint4*)(h + (long)e1.x * HID_DIM))[li]; }
        if (v2) { e2 = csc[p + 8]; r2 = ((const uint4*)(h + (long)e2.x * HID_DIM))[li]; }
        if (v0) acc8(a0, r0, __int_as_float(e0.y));
        if (v1) acc8(a1, r1, __int_as_float(e1.y));
        if (v2) acc8(a2, r2, __int_as_float(e2.y));
    }
#pragma unroll
    for (int j = 0; j < 8; j++) a0[j] += (a1[j] + a2[j]) + a3[j];
#pragma unroll
    for (int j = 0; j < 8; j++) a0[j] += __shfl_down(a0[j], 32);
#pragma unroll
    for (int j = 0; j < 8; j++) a0[j] += __shfl_down(a0[j], 16);
    if (strm == 0) {
        float4 bv0 = ((const float4*)b)[li * 2];
        float4 bv1 = ((const float4*)b)[li * 2 + 1];
        float4 o0 = make_float4(fmaxf(di * a0[0] + bv0.x, 0.f), fmaxf(di * a0[1] + bv0.y, 0.f),
                                fmaxf(di * a0[2] + bv0.z, 0.f), fmaxf(di * a0[3] + bv0.w, 0.f));
        float4 o1 = make_float4(fmaxf(di * a0[4] + bv1.x, 0.f), fmaxf(di * a0[5] + bv1.y, 0.f),
                                fmaxf(di * a0[6] + bv1.z, 0.f), fmaxf(di * a0[7] + bv1.w, 0.f));
        float4* dst = (float4*)(out + (long)node * HID_DIM);
        dst[li * 2] = o0;
        dst[li * 2 + 1] = o1;
    }
}

// ---------------- aggregation layer 2 (D=64 fp16 in, fp32 out, +bias) ----------

__global__ __launch_bounds__(256) void agg2_kernel(const __half* __restrict__ h,
        const float* __restrict__ dinv, const int* __restrict__ offsets,
        const int2* __restrict__ csc, const float* __restrict__ b,
        float* __restrict__ out, int n) {
    int t = threadIdx.x;
    int lane = t & 63;
    int strm = lane >> 4;            // 0..3
    int li = lane & 15;              // half4 index in row (16*4 = 64 dims)
    int node = blockIdx.x * 4 + (t >> 6);
    if (node >= n) return;

    float di = dinv[node];
    float a0[4] = {0,0,0,0};
    float a1[4] = {0,0,0,0};
    float a2[4] = {0,0,0,0};
    float a3[4] = {0,0,0,0};
    int s = offsets[node], e = offsets[node + 1];

    if (strm == 0) {
        uint2 raw = ((const uint2*)(h + (long)node * OUT_DIM))[li];
        acc4h(a0, raw, di);
    }

    int p = s + strm;
    for (; p + 12 < e; p += 16) {
        int2 e0 = csc[p], e1 = csc[p + 4], e2 = csc[p + 8], e3 = csc[p + 12];
        uint2 r0 = ((const uint2*)(h + (long)e0.x * OUT_DIM))[li];
        uint2 r1 = ((const uint2*)(h + (long)e1.x * OUT_DIM))[li];
        uint2 r2 = ((const uint2*)(h + (long)e2.x * OUT_DIM))[li];
        uint2 r3 = ((const uint2*)(h + (long)e3.x * OUT_DIM))[li];
        acc4h(a0, r0, __int_as_float(e0.y));
        acc4h(a1, r1, __int_as_float(e1.y));
        acc4h(a2, r2, __int_as_float(e2.y));
        acc4h(a3, r3, __int_as_float(e3.y));
    }
    {
        bool v0 = (p < e), v1 = (p + 4 < e), v2 = (p + 8 < e);
        int2 e0, e1, e2;
        uint2 r0, r1, r2;
        if (v0) { e0 = csc[p];     r0 = ((const uint2*)(h + (long)e0.x * OUT_DIM))[li]; }
        if (v1) { e1 = csc[p + 4]; r1 = ((const uint2*)(h + (long)e1.x * OUT_DIM))[li]; }
        if (v2) { e2 = csc[p + 8]; r2 = ((const uint2*)(h + (long)e2.x * OUT_DIM))[li]; }
        if (v0) acc4h(a0, r0, __int_as_float(e0.y));
        if (v1) acc4h(a1, r1, __int_as_float(e1.y));
        if (v2) acc4h(a2, r2, __int_as_float(e2.y));
    }
#pragma unroll
    for (int j = 0; j < 4; j++) a0[j] += (a1[j] + a2[j]) + a3[j];
#pragma unroll
    for (int j = 0; j < 4; j++) a0[j] += __shfl_down(a0[j], 32);
#pragma unroll
    for (int j = 0; j < 4; j++) a0[j] += __shfl_down(a0[j], 16);
    if (strm == 0) {
        float4 bv = ((const float4*)b)[li];
        ((float4*)(out + (long)node * OUT_DIM))[li] =
            make_float4(di * a0[0] + bv.x, di * a0[1] + bv.y,
                        di * a0[2] + bv.z, di * a0[3] + bv.w);
    }
}

// ---------------- launch ----------------

extern "C" void kernel_launch(void* const* d_in, const int* in_sizes, int n_in,
                              void* d_out, int out_size, void* d_ws, size_t ws_size,
                              hipStream_t stream) {
    const float* x  = (const float*)d_in[0];
    const int*   ei = (const int*)d_in[1];
    const float* w  = (const float*)d_in[2];
    const float* W1 = (const float*)d_in[3];
    const float* b1 = (const float*)d_in[4];
    const float* W2 = (const float*)d_in[5];
    const float* b2 = (const float*)d_in[6];
    float* out = (float*)d_out;

    int N = in_sizes[0] / IN_DIM;       // 100000
    int E = in_sizes[2];                // 1600000
    const int* row = ei;
    const int* col = ei + E;

    char* base = (char*)d_ws;
    size_t off = 0;
    auto alloc = [&](size_t bytes) -> void* {
        void* p = base + off;
        off += (bytes + 255) & ~(size_t)255;
        return p;
    };
    unsigned long long* packed = (unsigned long long*)alloc((size_t)N * 8);
    float* dinv     = (float*)alloc((size_t)N * 4);
    int*   cnt      = (int*)  alloc((size_t)N * 4);
    int*   offsets  = (int*)  alloc((size_t)(N + 1) * 4);
    int*   arr      = (int*)  alloc((size_t)E * 4);
    int*   bsum     = (int*)  alloc((size_t)1024 * 4);
    int2*  csc      = (int2*) alloc((size_t)E * 8);
    __half* h       = (__half*)alloc((size_t)N * HID_DIM * 2);  // fp16; reused for h2
    float* hagg     = (float*)alloc((size_t)N * HID_DIM * 4);
    unsigned short* wt1h = (unsigned short*)alloc((size_t)IN_DIM * HID_DIM * 2);
    unsigned short* wt1l = (unsigned short*)alloc((size_t)IN_DIM * HID_DIM * 2);
    unsigned short* wt2h = (unsigned short*)alloc((size_t)HID_DIM * OUT_DIM * 2);
    unsigned short* wt2l = (unsigned short*)alloc((size_t)HID_DIM * OUT_DIM * 2);

    int gN = (N + 255) / 256;
    int gE = (E + 255) / 256;
    int gGemm = (N + 127) / 128;        // 128-row tiles, 128-thread blocks
    int gDeg  = (E + 1023) / 1024;      // 1024 edges per deg-role block
    int gAgg = (N + 3) / 4;
    int nbScan = (N + 1023) / 1024;

    wsplit_kernel<<<(IN_DIM * HID_DIM + 255) / 256, 256, 0, stream>>>(
        W1, wt1h, wt1l, IN_DIM, HID_DIM);
    wsplit_kernel<<<(HID_DIM * OUT_DIM + 255) / 256, 256, 0, stream>>>(
        W2, wt2h, wt2l, HID_DIM, OUT_DIM);
    init_kernel<<<gN, 256, 0, stream>>>(packed, N);
    // fused: GEMM1 (blocks [0,gGemm)) + per-edge deg atomics (blocks [gGemm, gGemm+gDeg))
    gemm_deg_kernel<IN_DIM, HID_DIM, true><<<gGemm + gDeg, 128, 0, stream>>>(
        x, wt1h, wt1l, h, N, gGemm, col, w, packed, arr, E);
    dinv_kernel<<<gN, 256, 0, stream>>>(packed, dinv, cnt, N);
    scan1_kernel<<<nbScan, 256, 0, stream>>>(cnt, bsum, N);
    scan2_kernel<<<1, 1024, 0, stream>>>(bsum, offsets + N, nbScan);
    scan3_kernel<<<nbScan, 256, 0, stream>>>(cnt, bsum, offsets, N);
    fill_csc_kernel<<<gE, 256, 0, stream>>>(row, col, w, dinv, offsets, arr, csc, E);
    agg1_kernel<<<gAgg, 256, 0, stream>>>(h, dinv, offsets, csc, b1, hagg, N);
    gemm_deg_kernel<HID_DIM, OUT_DIM, false><<<gGemm, 128, 0, stream>>>(
        hagg, wt2h, wt2l, h, N, gGemm, col, w, packed, arr, E);
    agg2_kernel<<<gAgg, 256, 0, stream>>>(h, dinv, offsets, csc, b2, out, N);
}

// Round 6
// 409.790 us; speedup vs baseline: 1.0657x; 1.0657x over previous
//
#include <hip/hip_runtime.h>
#include <hip/hip_fp16.h>
#include <hip/hip_bf16.h>

#define IN_DIM 256
#define HID_DIM 128
#define OUT_DIM 64

typedef short s8v __attribute__((ext_vector_type(8)));
typedef float f32x4 __attribute__((ext_vector_type(4)));

// ---------------- bf16 split helpers ----------------

__device__ __forceinline__ unsigned short bf16_rne(float f) {
    unsigned int u = __float_as_uint(f);
    u += 0x7FFFu + ((u >> 16) & 1u);
    return (unsigned short)(u >> 16);
}
__device__ __forceinline__ float bfbits_to_f(unsigned short h) {
    return __uint_as_float(((unsigned int)h) << 16);
}

// 8 consecutive floats -> hi/lo bf16 fragments via v_cvt_pk_bf16_f32
__device__ __forceinline__ void cvt_split8(float4 f0, float4 f1, s8v& hi, s8v& lo) {
    float fv[8] = {f0.x, f0.y, f0.z, f0.w, f1.x, f1.y, f1.z, f1.w};
    unsigned int hw[4], lw[4];
#pragma unroll
    for (int i = 0; i < 4; i++) {
        __hip_bfloat162 hh = __float22bfloat162_rn(make_float2(fv[2*i], fv[2*i+1]));
        unsigned int hb = *(unsigned int*)&hh;
        float r0 = __uint_as_float(hb << 16);
        float r1 = __uint_as_float(hb & 0xffff0000u);
        __hip_bfloat162 ll = __float22bfloat162_rn(
            make_float2(fv[2*i] - r0, fv[2*i+1] - r1));
        hw[i] = hb;
        lw[i] = *(unsigned int*)&ll;
    }
    hi = *(s8v*)hw;
    lo = *(s8v*)lw;
}

// ---------------- fused prep: wsplit(W1) + wsplit(W2) + init(packed) --------
// All jobs are index-disjoint writes; one dispatch replaces three + offsets[N]=E.

#define FPSCALE 16777216.0f
#define FPMASK  ((1ULL << 40) - 1)

__global__ __launch_bounds__(256) void prep_kernel(
        const float* __restrict__ W1, const float* __restrict__ W2,
        unsigned short* __restrict__ wt1h, unsigned short* __restrict__ wt1l,
        unsigned short* __restrict__ wt2h, unsigned short* __restrict__ wt2l,
        unsigned long long* __restrict__ packed, int* __restrict__ offsets,
        int n, int e) {
    int idx = blockIdx.x * 256 + threadIdx.x;
    if (idx < IN_DIM * HID_DIM) {          // W1 split, transpose to [HID][IN]
        int k = idx / HID_DIM, nn = idx % HID_DIM;
        float f = W1[idx];
        unsigned short h = bf16_rne(f);
        unsigned short l = bf16_rne(f - bfbits_to_f(h));
        wt1h[nn * IN_DIM + k] = h;
        wt1l[nn * IN_DIM + k] = l;
    }
    if (idx < HID_DIM * OUT_DIM) {         // W2 split, transpose to [OUT][HID]
        int k = idx / OUT_DIM, nn = idx % OUT_DIM;
        float f = W2[idx];
        unsigned short h = bf16_rne(f);
        unsigned short l = bf16_rne(f - bfbits_to_f(h));
        wt2h[nn * HID_DIM + k] = h;
        wt2l[nn * HID_DIM + k] = l;
    }
    if (idx < n) packed[idx] = (1ULL << 24);   // deg = 1.0 (self-loop), cnt = 0
    if (idx == 0) offsets[n] = e;              // scan total is statically E
}

// ---------------- fused dinv + scan1 ----------------------------------------
// Per block: 1024 nodes. Computes dinv + cnt inline, then block tree-reduce of
// cnt -> bsum[blockIdx] (raw block sums; prefixes are recomputed locally in
// scan3 — nbScan=98 <= 256 makes that cheaper than a scan2 dispatch).

__global__ __launch_bounds__(256) void dinv_scan1_kernel(
        const unsigned long long* __restrict__ packed,
        float* __restrict__ dinv, int* __restrict__ cnt,
        int* __restrict__ bsum, int n) {
    int t = threadIdx.x;
    int base = blockIdx.x * 1024 + t * 4;
    int s = 0;
    if (base + 3 < n) {
        float dv[4]; int cv[4];
#pragma unroll
        for (int i = 0; i < 4; i++) {
            unsigned long long p = packed[base + i];
            float d = (float)(p & FPMASK) * (1.0f / FPSCALE);
            dv[i] = d > 0.0f ? rsqrtf(d) : 0.0f;
            cv[i] = (int)(p >> 40);
            s += cv[i];
        }
        *(float4*)(dinv + base) = make_float4(dv[0], dv[1], dv[2], dv[3]);
        *(int4*)(cnt + base)    = make_int4(cv[0], cv[1], cv[2], cv[3]);
    } else {
        for (int i = 0; i < 4; i++) {
            if (base + i < n) {
                unsigned long long p = packed[base + i];
                float d = (float)(p & FPMASK) * (1.0f / FPSCALE);
                dinv[base + i] = d > 0.0f ? rsqrtf(d) : 0.0f;
                int c = (int)(p >> 40);
                cnt[base + i] = c;
                s += c;
            }
        }
    }
    __shared__ int sm[256];
    sm[t] = s;
    __syncthreads();
#pragma unroll
    for (int d = 128; d > 0; d >>= 1) {
        if (t < d) sm[t] += sm[t + d];
        __syncthreads();
    }
    if (t == 0) bsum[blockIdx.x] = sm[0];
}

// ---------------- scan3 with inline global-prefix (replaces scan2+scan3) ----

__global__ __launch_bounds__(256) void scan3_kernel(const int* __restrict__ cnt,
        const int* __restrict__ bsum, int* __restrict__ offsets, int n, int nb) {
    int t = threadIdx.x;
    // global prefix for this block: sum of bsum[j], j < blockIdx.x (nb <= 256)
    __shared__ int smb[256];
    smb[t] = (t < (int)blockIdx.x) ? bsum[t] : 0;
    __syncthreads();
#pragma unroll
    for (int d = 128; d > 0; d >>= 1) {
        if (t < d) smb[t] += smb[t + d];
        __syncthreads();
    }
    int gbase = smb[0];
    __syncthreads();

    int base = blockIdx.x * 1024 + t * 4;
    int a[4] = {0, 0, 0, 0};
    if (base + 3 < n) {
        int4 v = *(const int4*)(cnt + base);
        a[0] = v.x; a[1] = v.y; a[2] = v.z; a[3] = v.w;
    } else {
        for (int i = 0; i < 4; i++) if (base + i < n) a[i] = cnt[base + i];
    }
    int s = a[0] + a[1] + a[2] + a[3];
    __shared__ int sm[256];
    sm[t] = s;
    __syncthreads();
    for (int d = 1; d < 256; d <<= 1) {
        int u = (t >= d) ? sm[t - d] : 0;
        __syncthreads();
        sm[t] += u;
        __syncthreads();
    }
    int pre = gbase + ((t == 0) ? 0 : sm[t - 1]);
    int o0 = pre, o1 = o0 + a[0], o2 = o1 + a[1], o3 = o2 + a[2];
    if (base + 3 < n) {
        *(int4*)(offsets + base) = make_int4(o0, o1, o2, o3);
    } else {
        int o[4] = {o0, o1, o2, o3};
        for (int i = 0; i < 4; i++) if (base + i < n) offsets[base + i] = o[i];
    }
}

// CSC entry: int2{ src_row, float_bits(w * dinv[src]) }.
// No atomic: slot = offsets[col] + arrival index from the fused deg pass.

__global__ __launch_bounds__(256) void fill_csc_kernel(const int* __restrict__ row,
        const int* __restrict__ col, const float* __restrict__ w,
        const float* __restrict__ dinv,
        const int* __restrict__ offsets, const int* __restrict__ arr,
        int2* __restrict__ csc, int e) {
    int i = blockIdx.x * 256 + threadIdx.x;
    if (i < e) {
        int c = col[i];
        int r = row[i];
        int p = offsets[c] + arr[i];
        csc[p] = make_int2(r, __float_as_int(w[i] * dinv[r]));
    }
}

// ---------------- fused MFMA GEMM + deg/cnt atomics -------------------------
// Blocks [0, gemmBlocks): split-bf16 GEMM (M=64/wave, XOR-swizzled B staging
// via global_load_lds, A global->reg). Writes UNSCALED x@W in fp16.
// Blocks [gemmBlocks, ...): 1024 edges/block, one u64 atomicAdd per edge
// (deg-sum + count + arrival index) — overlaps the atomic-unit latency under
// the GEMM's MFMA/LDS work (r4-verified: 94 us fused vs 75+45 serial).

template<int K, int NCOL, bool DEG>
__global__ __launch_bounds__(128, 2) void gemm_deg_kernel(
        const float* __restrict__ x, const unsigned short* __restrict__ wth,
        const unsigned short* __restrict__ wtl,
        __half* __restrict__ out, int n, int gemmBlocks,
        const int* __restrict__ colIdx, const float* __restrict__ ew,
        unsigned long long* packed, int* __restrict__ arr, int eCount) {
    constexpr int NT = NCOL / 16;          // 16-col tiles
    constexpr int NCH = K / 32;            // K chunks
    constexpr int NS = NCOL / 16;          // 16-row B segments per chunk

    __shared__ unsigned short sBh[2][NCOL][32];
    __shared__ unsigned short sBl[2][NCOL][32];

    int t = threadIdx.x;

    if (DEG && (int)blockIdx.x >= gemmBlocks) {
        // ---- edge-atomic role (r4 structure) ----
        long ebase = (long)((int)blockIdx.x - gemmBlocks) * 1024;
#pragma unroll
        for (int j = 0; j < 2; j++) {
            long i = ebase + j * 512 + t * 4;
            if (i + 3 < eCount) {
                int4 c4 = *(const int4*)(colIdx + i);
                float4 w4 = *(const float4*)(ew + i);
                unsigned long long o0 = atomicAdd(&packed[c4.x],
                    (1ULL << 40) | (unsigned long long)(w4.x * FPSCALE + 0.5f));
                unsigned long long o1 = atomicAdd(&packed[c4.y],
                    (1ULL << 40) | (unsigned long long)(w4.y * FPSCALE + 0.5f));
                unsigned long long o2 = atomicAdd(&packed[c4.z],
                    (1ULL << 40) | (unsigned long long)(w4.z * FPSCALE + 0.5f));
                unsigned long long o3 = atomicAdd(&packed[c4.w],
                    (1ULL << 40) | (unsigned long long)(w4.w * FPSCALE + 0.5f));
                *(int4*)(arr + i) = make_int4((int)(o0 >> 40), (int)(o1 >> 40),
                                              (int)(o2 >> 40), (int)(o3 >> 40));
            } else {
                for (int q = 0; q < 4; q++) {
                    long ii = i + q;
                    if (ii < eCount) {
                        unsigned long long v = (1ULL << 40) |
                            (unsigned long long)(ew[ii] * FPSCALE + 0.5f);
                        unsigned long long old = atomicAdd(&packed[colIdx[ii]], v);
                        arr[ii] = (int)(old >> 40);
                    }
                }
            }
        }
        return;
    }

    // ---- GEMM role ----
    int wave = t >> 6, lane = t & 63, quad = lane >> 4, r16 = lane & 15;
    long rowBase = (long)blockIdx.x * 128 + wave * 64;

    f32x4 acc[4][NT];
#pragma unroll
    for (int mi = 0; mi < 4; mi++)
#pragma unroll
        for (int nt = 0; nt < NT; nt++) acc[mi][nt] = (f32x4)0.0f;

    const float* pa[4];
#pragma unroll
    for (int mi = 0; mi < 4; mi++) {
        long r = rowBase + mi * 16 + r16;
        if (r > n - 1) r = n - 1;
        pa[mi] = x + r * K + quad * 8;
    }

    // staging: lane l writes phys (row=l>>2, slot=l&3); fetch logical slot =
    // phys ^ sw(row), sw(row)=(row>>1)&3  (both-sides XOR swizzle).
    int srcSlot = ((lane & 3) ^ ((lane >> 3) & 3)) * 8;   // in shorts
    int lrow = lane >> 2;

    auto stage = [&](int buf, int kc) {
#pragma unroll
        for (int j = 0; j < NS / 2; j++) {
            int s = wave + 2 * j;                 // 16-row segment id
            int r = s * 16 + lrow;                // B row (= output col)
            const unsigned short* gh = wth + (long)r * K + kc * 32 + srcSlot;
            const unsigned short* gl = wtl + (long)r * K + kc * 32 + srcSlot;
            __builtin_amdgcn_global_load_lds(
                (const __attribute__((address_space(1))) unsigned int*)gh,
                (__attribute__((address_space(3))) unsigned int*)&sBh[buf][s * 16][0],
                16, 0, 0);
            __builtin_amdgcn_global_load_lds(
                (const __attribute__((address_space(1))) unsigned int*)gl,
                (__attribute__((address_space(3))) unsigned int*)&sBl[buf][s * 16][0],
                16, 0, 0);
        }
    };

    // prologue: stage chunk 0, prefetch A chunk 0
    stage(0, 0);
    float4 a[8];
#pragma unroll
    for (int mi = 0; mi < 4; mi++) {
        a[2 * mi]     = *(const float4*)(pa[mi]);
        a[2 * mi + 1] = *(const float4*)(pa[mi] + 4);
    }
    __syncthreads();

    int rdSlot = (r16 >> 1) & 3;    // read-side swizzle component

    for (int kc = 0; kc < NCH; kc++) {
        int buf = kc & 1;
        if (kc + 1 < NCH) stage(buf ^ 1, kc + 1);   // B prefetch over MFMA

        s8v ah[4], al[4];
#pragma unroll
        for (int mi = 0; mi < 4; mi++)
            cvt_split8(a[2 * mi], a[2 * mi + 1], ah[mi], al[mi]);
        if (kc + 1 < NCH) {                          // A register prefetch
#pragma unroll
            for (int mi = 0; mi < 4; mi++) {
                const float* q = pa[mi] + (kc + 1) * 32;
                a[2 * mi]     = *(const float4*)(q);
                a[2 * mi + 1] = *(const float4*)(q + 4);
            }
        }
#pragma unroll
        for (int nt = 0; nt < NT; nt++) {
            int sl = (quad ^ rdSlot) * 8;
            s8v bh = *(const s8v*)&sBh[buf][nt * 16 + r16][sl];
            s8v bl = *(const s8v*)&sBl[buf][nt * 16 + r16][sl];
#pragma unroll
            for (int mi = 0; mi < 4; mi++) {
                acc[mi][nt] = __builtin_amdgcn_mfma_f32_16x16x32_bf16(ah[mi], bh, acc[mi][nt], 0, 0, 0);
                acc[mi][nt] = __builtin_amdgcn_mfma_f32_16x16x32_bf16(al[mi], bh, acc[mi][nt], 0, 0, 0);
                acc[mi][nt] = __builtin_amdgcn_mfma_f32_16x16x32_bf16(ah[mi], bl, acc[mi][nt], 0, 0, 0);
            }
        }
        __syncthreads();   // drains stage(kc+1) + flips buffers
    }

#pragma unroll
    for (int mi = 0; mi < 4; mi++) {
        long gr0 = rowBase + mi * 16 + quad * 4;
#pragma unroll
        for (int nt = 0; nt < NT; nt++) {
            f32x4 d = acc[mi][nt];
#pragma unroll
            for (int i = 0; i < 4; i++) {
                long gr = gr0 + i;
                if (gr < n) out[gr * NCOL + nt * 16 + r16] = __float2half(d[i]);
            }
        }
    }
}

// ---------------- fp16 gather accumulate helpers ----------------

__device__ __forceinline__ void acc8(float* a, uint4 raw, float w) {
    __half2* hp = (__half2*)&raw;
    float2 f0 = __half22float2(hp[0]);
    float2 f1 = __half22float2(hp[1]);
    float2 f2 = __half22float2(hp[2]);
    float2 f3 = __half22float2(hp[3]);
    a[0] += w * f0.x; a[1] += w * f0.y; a[2] += w * f1.x; a[3] += w * f1.y;
    a[4] += w * f2.x; a[5] += w * f2.y; a[6] += w * f3.x; a[7] += w * f3.y;
}

__device__ __forceinline__ void acc4h(float* a, uint2 raw, float w) {
    __half2* hp = (__half2*)&raw;
    float2 f0 = __half22float2(hp[0]);
    float2 f1 = __half22float2(hp[1]);
    a[0] += w * f0.x; a[1] += w * f0.y; a[2] += w * f1.x; a[3] += w * f1.y;
}

// ---------------- aggregation layer 1 (D=128 fp16 in, fp32 out, +bias, relu) ----
// h rows are UNSCALED; csc weight is w*dinv[src]; self weight dinv[node];
// final scale dinv[node].  (r4-verified structure.)

__global__ __launch_bounds__(256) void agg1_kernel(const __half* __restrict__ h,
        const float* __restrict__ dinv, const int* __restrict__ offsets,
        const int2* __restrict__ csc, const float* __restrict__ b,
        float* __restrict__ out, int n) {
    int t = threadIdx.x;
    int lane = t & 63;
    int strm = lane >> 4;            // 0..3
    int li = lane & 15;              // half8 index in row (16*8 = 128 dims)
    int node = blockIdx.x * 4 + (t >> 6);
    if (node >= n) return;

    float di = dinv[node];
    float a0[8] = {0,0,0,0,0,0,0,0};
    float a1[8] = {0,0,0,0,0,0,0,0};
    int s = offsets[node], e = offsets[node + 1];

    if (strm == 0) {                 // self-loop: weight dinv[node] * h[node]
        uint4 raw = ((const uint4*)(h + (long)node * HID_DIM))[li];
        acc8(a0, raw, di);
    }

    int p = s + strm;
    for (; p + 4 < e; p += 8) {
        int2 e0 = csc[p], e1 = csc[p + 4];
        uint4 r0 = ((const uint4*)(h + (long)e0.x * HID_DIM))[li];
        uint4 r1 = ((const uint4*)(h + (long)e1.x * HID_DIM))[li];
        acc8(a0, r0, __int_as_float(e0.y));
        acc8(a1, r1, __int_as_float(e1.y));
    }
    if (p < e) {
        int2 e0 = csc[p];
        uint4 r0 = ((const uint4*)(h + (long)e0.x * HID_DIM))[li];
        acc8(a0, r0, __int_as_float(e0.y));
    }
#pragma unroll
    for (int j = 0; j < 8; j++) a0[j] += a1[j];
#pragma unroll
    for (int j = 0; j < 8; j++) a0[j] += __shfl_down(a0[j], 32);
#pragma unroll
    for (int j = 0; j < 8; j++) a0[j] += __shfl_down(a0[j], 16);
    if (strm == 0) {
        float4 bv0 = ((const float4*)b)[li * 2];
        float4 bv1 = ((const float4*)b)[li * 2 + 1];
        float4 o0 = make_float4(fmaxf(di * a0[0] + bv0.x, 0.f), fmaxf(di * a0[1] + bv0.y, 0.f),
                                fmaxf(di * a0[2] + bv0.z, 0.f), fmaxf(di * a0[3] + bv0.w, 0.f));
        float4 o1 = make_float4(fmaxf(di * a0[4] + bv1.x, 0.f), fmaxf(di * a0[5] + bv1.y, 0.f),
                                fmaxf(di * a0[6] + bv1.z, 0.f), fmaxf(di * a0[7] + bv1.w, 0.f));
        float4* dst = (float4*)(out + (long)node * HID_DIM);
        dst[li * 2] = o0;
        dst[li * 2 + 1] = o1;
    }
}

// ---------------- aggregation layer 2 (D=64 fp16 in, fp32 out, +bias) ----------

__global__ __launch_bounds__(256) void agg2_kernel(const __half* __restrict__ h,
        const float* __restrict__ dinv, const int* __restrict__ offsets,
        const int2* __restrict__ csc, const float* __restrict__ b,
        float* __restrict__ out, int n) {
    int t = threadIdx.x;
    int lane = t & 63;
    int strm = lane >> 4;            // 0..3
    int li = lane & 15;              // half4 index in row (16*4 = 64 dims)
    int node = blockIdx.x * 4 + (t >> 6);
    if (node >= n) return;

    float di = dinv[node];
    float a0[4] = {0,0,0,0};
    float a1[4] = {0,0,0,0};
    int s = offsets[node], e = offsets[node + 1];

    if (strm == 0) {
        uint2 raw = ((const uint2*)(h + (long)node * OUT_DIM))[li];
        acc4h(a0, raw, di);
    }

    int p = s + strm;
    for (; p + 4 < e; p += 8) {
        int2 e0 = csc[p], e1 = csc[p + 4];
        uint2 r0 = ((const uint2*)(h + (long)e0.x * OUT_DIM))[li];
        uint2 r1 = ((const uint2*)(h + (long)e1.x * OUT_DIM))[li];
        acc4h(a0, r0, __int_as_float(e0.y));
        acc4h(a1, r1, __int_as_float(e1.y));
    }
    if (p < e) {
        int2 e0 = csc[p];
        uint2 r0 = ((const uint2*)(h + (long)e0.x * OUT_DIM))[li];
        acc4h(a0, r0, __int_as_float(e0.y));
    }
#pragma unroll
    for (int j = 0; j < 4; j++) a0[j] += a1[j];
#pragma unroll
    for (int j = 0; j < 4; j++) a0[j] += __shfl_down(a0[j], 32);
#pragma unroll
    for (int j = 0; j < 4; j++) a0[j] += __shfl_down(a0[j], 16);
    if (strm == 0) {
        float4 bv = ((const float4*)b)[li];
        ((float4*)(out + (long)node * OUT_DIM))[li] =
            make_float4(di * a0[0] + bv.x, di * a0[1] + bv.y,
                        di * a0[2] + bv.z, di * a0[3] + bv.w);
    }
}

// ---------------- launch (8 dispatches, was 13) ----------------

extern "C" void kernel_launch(void* const* d_in, const int* in_sizes, int n_in,
                              void* d_out, int out_size, void* d_ws, size_t ws_size,
                              hipStream_t stream) {
    const float* x  = (const float*)d_in[0];
    const int*   ei = (const int*)d_in[1];
    const float* w  = (const float*)d_in[2];
    const float* W1 = (const float*)d_in[3];
    const float* b1 = (const float*)d_in[4];
    const float* W2 = (const float*)d_in[5];
    const float* b2 = (const float*)d_in[6];
    float* out = (float*)d_out;

    int N = in_sizes[0] / IN_DIM;       // 100000
    int E = in_sizes[2];                // 1600000
    const int* row = ei;
    const int* col = ei + E;

    char* base = (char*)d_ws;
    size_t off = 0;
    auto alloc = [&](size_t bytes) -> void* {
        void* p = base + off;
        off += (bytes + 255) & ~(size_t)255;
        return p;
    };
    unsigned long long* packed = (unsigned long long*)alloc((size_t)N * 8);
    float* dinv     = (float*)alloc((size_t)N * 4);
    int*   cnt      = (int*)  alloc((size_t)N * 4);
    int*   offsets  = (int*)  alloc((size_t)(N + 1) * 4);
    int*   arr      = (int*)  alloc((size_t)E * 4);
    int*   bsum     = (int*)  alloc((size_t)1024 * 4);
    int2*  csc      = (int2*) alloc((size_t)E * 8);
    __half* h       = (__half*)alloc((size_t)N * HID_DIM * 2);  // fp16; reused for h2
    float* hagg     = (float*)alloc((size_t)N * HID_DIM * 4);
    unsigned short* wt1h = (unsigned short*)alloc((size_t)IN_DIM * HID_DIM * 2);
    unsigned short* wt1l = (unsigned short*)alloc((size_t)IN_DIM * HID_DIM * 2);
    unsigned short* wt2h = (unsigned short*)alloc((size_t)HID_DIM * OUT_DIM * 2);
    unsigned short* wt2l = (unsigned short*)alloc((size_t)HID_DIM * OUT_DIM * 2);

    int gN = (N + 255) / 256;
    int gE = (E + 255) / 256;
    int gGemm = (N + 127) / 128;        // 128-row tiles, 128-thread blocks
    int gDeg  = (E + 1023) / 1024;      // 1024 edges per deg-role block
    int gAgg = (N + 3) / 4;
    int nbScan = (N + 1023) / 1024;     // 98 (<= 256 required by scan3)

    // 1) weight splits + packed init + offsets[N]=E
    prep_kernel<<<gN, 256, 0, stream>>>(W1, W2, wt1h, wt1l, wt2h, wt2l,
                                        packed, offsets, N, E);
    // 2) fused: GEMM1 (blocks [0,gGemm)) + per-edge deg atomics
    gemm_deg_kernel<IN_DIM, HID_DIM, true><<<gGemm + gDeg, 128, 0, stream>>>(
        x, wt1h, wt1l, h, N, gGemm, col, w, packed, arr, E);
    // 3) dinv + per-block cnt sums
    dinv_scan1_kernel<<<nbScan, 256, 0, stream>>>(packed, dinv, cnt, bsum, N);
    // 4) offsets (global prefix recomputed in-block; no scan2 dispatch)
    scan3_kernel<<<nbScan, 256, 0, stream>>>(cnt, bsum, offsets, N, nbScan);
    // 5) CSC fill (deterministic slots)
    fill_csc_kernel<<<gE, 256, 0, stream>>>(row, col, w, dinv, offsets, arr, csc, E);
    // 6) aggregate layer 1 (+bias, relu)
    agg1_kernel<<<gAgg, 256, 0, stream>>>(h, dinv, offsets, csc, b1, hagg, N);
    // 7) GEMM2
    gemm_deg_kernel<HID_DIM, OUT_DIM, false><<<gGemm, 128, 0, stream>>>(
        hagg, wt2h, wt2l, h, N, gGemm, col, w, packed, arr, E);
    // 8) aggregate layer 2 (+bias)
    agg2_kernel<<<gAgg, 256, 0, stream>>>(h, dinv, offsets, csc, b2, out, N);
}